// Round 10
// baseline (35766.382 us; speedup 1.0000x reference)
//
#include <hip/hip_runtime.h>
#include <hip/hip_fp16.h>

// ---------------- types ----------------
typedef short bf16x8 __attribute__((ext_vector_type(8)));
typedef float f32x4  __attribute__((ext_vector_type(4)));
typedef _Float16 h2_t __attribute__((ext_vector_type(2)));

#define T_ 512
#define B_ 64
#define I_ 128
#define H_ 256
#define L_ 6
#define M_ 32768  // T*B

// ---- workspace offsets (bytes), all 256-aligned ----
static constexpr size_t XG_OFF    = 0;
static constexpr size_t X0_OFF    = 100663296;
static constexpr size_t YA_OFF    = 109051904;
static constexpr size_t YB_OFF    = 142606336;
static constexpr size_t WIH0_OFF  = 176160768;
static constexpr size_t WIHR_OFF  = 176553984;
static constexpr size_t WSCAN_OFF = 184418304;
static constexpr size_t BIAS_OFF  = 189136896;

// ---------------- prep kernels ----------------
__global__ void cvt_bf16(const float* __restrict__ s, unsigned short* __restrict__ d, int n) {
  for (int i = blockIdx.x * blockDim.x + threadIdx.x; i < n; i += gridDim.x * blockDim.x) {
    unsigned u = __builtin_bit_cast(unsigned, s[i]);
    u += 0x7fffu + ((u >> 16) & 1u);
    d[i] = (unsigned short)(u >> 16);
  }
}

// wscan[ld][half][g][j][r] = (f16(w_hh[g*256+j][2R]), f16(w_hh[g*256+j][2R+1])), R=half*64+r
// -> per-thread weights are r-CONTIGUOUS: 16 dwordx4 loads per gate per step.
__global__ void prep_wscan(const float* __restrict__ whh0, const float* __restrict__ whhr,
                           unsigned int* __restrict__ out) {
  int idx = blockIdx.x * 256 + threadIdx.x;            // 12*2*3*256*64 = 1179648 exact
  int ld   = idx / 98304;
  int rem  = idx - ld * 98304;
  int half = rem / 49152;
  int rem2 = rem - half * 49152;
  int g    = rem2 >> 14;
  int j    = (rem2 >> 6) & 255;
  int r    = rem2 & 63;
  const float* src = (ld < 2) ? (whh0 + (size_t)ld * 196608) : (whhr + (size_t)(ld - 2) * 196608);
  const float* row = src + (size_t)(g * 256 + j) * 256;
  const int R = half * 64 + r;
  h2_t p; p[0] = (_Float16)row[2 * R]; p[1] = (_Float16)row[2 * R + 1];
  out[idx] = __builtin_bit_cast(unsigned int, p);
}

// bias4[ld][c][j]: c0 = bih_r+bhh_r, c1 = bih_z+bhh_z, c2 = bih_n, c3 = bhh_n
__global__ void prep_bias(const float* __restrict__ bih0, const float* __restrict__ bhh0,
                          const float* __restrict__ bihr, const float* __restrict__ bhhr,
                          float* __restrict__ out) {
  int idx = blockIdx.x * 256 + threadIdx.x;            // 12*4*256 = 12288 exact
  int ld = idx >> 10;
  int c  = (idx >> 8) & 3;
  int j  = idx & 255;
  const float* bi = (ld < 2) ? bih0 + ld * 768 : bihr + (ld - 2) * 768;
  const float* bh = (ld < 2) ? bhh0 + ld * 768 : bhhr + (ld - 2) * 768;
  float v;
  if (c == 0)      v = bi[j] + bh[j];
  else if (c == 1) v = bi[256 + j] + bh[256 + j];
  else if (c == 2) v = bi[512 + j];
  else             v = bh[512 + j];
  out[idx] = v;
}

// ---------------- GEMM: C[m,g] = sum_k A[m,k]*W[g,k], bf16 in, f16 out ----------------
__device__ __forceinline__ void llds16(const void* g, void* l) {
  __builtin_amdgcn_global_load_lds((const __attribute__((address_space(1))) void*)g,
                                   (__attribute__((address_space(3))) void*)l, 16, 0, 0);
}

__global__ __launch_bounds__(256)
void gemm_bt(const unsigned short* __restrict__ A,    // [M][K] bf16
             const unsigned short* __restrict__ Wl,   // [2][768][K] bf16
             __half* __restrict__ xg,                 // [2][M][768] f16
             int K) {
  const int m0 = blockIdx.x * 128;
  const int n0 = blockIdx.y * 128;
  const int d  = blockIdx.z;
  const unsigned short* W = Wl + (size_t)d * 768 * K;
  __half* C = xg + (size_t)d * M_ * 768;

  __shared__ short As[128 * 64];
  __shared__ short Bs[128 * 64];

  const int tid  = threadIdx.x;
  const int lane = tid & 63;

  const int wv = tid >> 6;
  const int wm = wv >> 1, wn = wv & 1;   // 2x2 wave grid, 64x64 per wave

  f32x4 acc[4][4] = {};

  for (int kt = 0; kt < K; kt += 64) {
#pragma unroll
    for (int i = 0; i < 4; i++) {        // stage A tile (128x64)
      int e = i * 256 + tid;
      int r = e >> 3, c = (e & 7) << 3;
      llds16(A + (size_t)(m0 + r) * K + kt + c, &As[e * 8]);
    }
#pragma unroll
    for (int i = 0; i < 4; i++) {        // stage W tile (128x64)
      int e = i * 256 + tid;
      int r = e >> 3, c = (e & 7) << 3;
      llds16(W + (size_t)(n0 + r) * K + kt + c, &Bs[e * 8]);
    }
    __syncthreads();
#pragma unroll
    for (int kf = 0; kf < 2; ++kf) {
      bf16x8 a[4], b[4];
      const int krow = kf * 32 + ((lane >> 4) << 3);
#pragma unroll
      for (int f = 0; f < 4; ++f)
        a[f] = *(const bf16x8*)&As[(wm * 64 + f * 16 + (lane & 15)) * 64 + krow];
#pragma unroll
      for (int f = 0; f < 4; ++f)
        b[f] = *(const bf16x8*)&Bs[(wn * 64 + f * 16 + (lane & 15)) * 64 + krow];
#pragma unroll
      for (int i = 0; i < 4; i++)
#pragma unroll
        for (int jn = 0; jn < 4; jn++)
          acc[i][jn] = __builtin_amdgcn_mfma_f32_16x16x32_bf16(a[i], b[jn], acc[i][jn], 0, 0, 0);
    }
    __syncthreads();
  }
  // epilogue: D col = lane&15, row = (lane>>4)*4 + v
#pragma unroll
  for (int i = 0; i < 4; i++) {
    const int row_b = m0 + wm * 64 + i * 16 + ((lane >> 4) << 2);
#pragma unroll
    for (int jn = 0; jn < 4; jn++) {
      const int col = n0 + wn * 64 + jn * 16 + (lane & 15);
#pragma unroll
      for (int v = 0; v < 4; ++v)
        C[(size_t)(row_b + v) * 768 + col] = __float2half(acc[i][jn][v]);
    }
  }
}

// ---------------- recurrent scan: one WG per (batch-PAIR, dir) ----------------
// NB=2 weight-stream amortization: r2..r9 established (a) weights CANNOT be
// resident (393KB > any on-CU storage), (b) r8's 574us == chip-L2 roofline at
// 50MB/step (128 WGs x 393KB). With 2 chains per WG the same 393KB stream
// serves 2 batches: chip-L2 demand halves to 25MB/step; VALU doubles to
// ~1700cy/step == L2 time (balanced). Weights load as dwordx4 (r-contiguous
// layout), used, discarded. 64 WGs, 512 threads, thread (j, half).
#define FDOT2(a, b, c) __builtin_amdgcn_fdot2((a), (b), (c), false)
#define BC2(u) __builtin_bit_cast(h2_t, (u))

__device__ __forceinline__ float dpp_xor1(float x) {
  // quad_perm [1,0,3,2] = 0xB1 : swap adjacent lanes (VALU pipe, not LDS)
  int r = __builtin_amdgcn_update_dpp(0, __builtin_bit_cast(int, x), 0xB1, 0xF, 0xF, true);
  return __builtin_bit_cast(float, r);
}

__device__ __forceinline__ unsigned short f16bits(float f) {
  return __half_as_ushort(__float2half(f));
}

__global__
__attribute__((amdgpu_flat_work_group_size(512, 512)))
__attribute__((amdgpu_waves_per_eu(2, 2)))
void gru_scan3(const unsigned int* __restrict__ wscan,  // [12][2][3][256][64]
               const float* __restrict__ bias4,         // [12][4][256]
               const __half* __restrict__ xg,           // [2][M][768]
               const float* __restrict__ h0,            // [12][64][256]
               unsigned short* __restrict__ yout,       // [M][512] bf16 (next-layer input)
               float* __restrict__ dout,                // d_out base (f32)
               int layer, int last) {
  const int tid  = threadIdx.x;
  const int j    = tid >> 1;    // h column / gate triple owner
  const int half = tid & 1;     // K-half
  const int bg   = blockIdx.x;  // batch pair
  const int b0   = bg * 2, b1 = b0 + 1;
  const int d    = blockIdx.y;  // direction
  const int ld   = layer * 2 + d;

  // weight base: [ld][half][g][j][r], gate stride 16384 dwords
  const unsigned int* wbase =
      wscan + ((size_t)(ld * 2 + half) * 3) * 16384 + (size_t)j * 64;

  const float* bb = bias4 + ld * 1024;
  const float bR = bb[j], bZ = bb[256 + j], bXn = bb[512 + j], bHn = bb[768 + j];

  __shared__ __attribute__((aligned(16))) char hbc[2][2][512];  // [buf][m][256 f16, swizzled]

  // swizzled byte offset for h[j] (upper 256B block gets bit4 flipped)
  const int wboff   = (j * 2) ^ ((j & 128) >> 3);
  const int halfoff = half << 8;

  float hr0 = h0[(size_t)ld * 16384 + b0 * 256 + j];
  float hr1 = h0[(size_t)ld * 16384 + b1 * 256 + j];
  if (half == 0) {
    *(unsigned short*)(&hbc[0][0][0] + wboff) = f16bits(hr0);
    *(unsigned short*)(&hbc[0][1][0] + wboff) = f16bits(hr1);
  }

  const __half* xgd = xg + (size_t)d * M_ * 768;
  const __half* xth = xgd + (size_t)b0 * 768 + j;
  const int t0 = d ? 511 : 0;
  {
  }
  size_t xo = (size_t)t0 * 49152;
  __half cxr0 = xth[xo], cxz0 = xth[xo + 256], cxn0 = xth[xo + 512];
  __half cxr1 = xth[xo + 768], cxz1 = xth[xo + 1024], cxn1 = xth[xo + 1280];

  __syncthreads();

  for (int s = 0; s < 512; s++) {
    const int cur = s & 1;
    // prefetch next step's xg (both batches)
    const int sn = (s + 1) & 511;
    const int t1 = d ? 511 - sn : sn;
    const size_t xo1 = (size_t)t1 * 49152;
    const __half nxr0 = xth[xo1], nxz0 = xth[xo1 + 256], nxn0 = xth[xo1 + 512];
    const __half nxr1 = xth[xo1 + 768], nxz1 = xth[xo1 + 1024], nxn1 = xth[xo1 + 1280];

    // opaque per-step weight base: loads stay in-loop (stream), no hoist+spill
    const unsigned int* wp = wbase;
    asm volatile("" : "+v"(wp));

    float ar0 = 0.f, az0 = 0.f, an0 = 0.f;
    float ar1 = 0.f, az1 = 0.f, an1 = 0.f;
    const char* rb = &hbc[cur][0][0];

#pragma unroll
    for (int c = 0; c < 16; c++) {
      const uint4 wr4 = *(const uint4*)(wp + 4 * c);
      const uint4 wz4 = *(const uint4*)(wp + 16384 + 4 * c);
      const uint4 wn4 = *(const uint4*)(wp + 32768 + 4 * c);
      const uint4 h0v = *(const uint4*)(rb + halfoff + (((c ^ half)) << 4));
      const uint4 h1v = *(const uint4*)(rb + 512 + halfoff + (((c ^ half)) << 4));
#pragma unroll
      for (int e = 0; e < 4; e++) {
        const unsigned he0 = (&h0v.x)[e], he1 = (&h1v.x)[e];
        const unsigned wre = (&wr4.x)[e], wze = (&wz4.x)[e], wne = (&wn4.x)[e];
        ar0 = FDOT2(BC2(he0), BC2(wre), ar0);
        az0 = FDOT2(BC2(he0), BC2(wze), az0);
        an0 = FDOT2(BC2(he0), BC2(wne), an0);
        ar1 = FDOT2(BC2(he1), BC2(wre), ar1);
        az1 = FDOT2(BC2(he1), BC2(wze), az1);
        an1 = FDOT2(BC2(he1), BC2(wne), an1);
      }
    }

    // combine K-halves: partner is the adjacent lane
    ar0 += dpp_xor1(ar0); az0 += dpp_xor1(az0); an0 += dpp_xor1(an0);
    ar1 += dpp_xor1(ar1); az1 += dpp_xor1(az1); an1 += dpp_xor1(an1);

    // gate math, batch 0
    {
      const float prer = ar0 + __half2float(cxr0) + bR;
      const float prez = az0 + __half2float(cxz0) + bZ;
      const float r = __builtin_amdgcn_rcpf(1.f + __builtin_amdgcn_exp2f(-1.44269504f * prer));
      const float z = __builtin_amdgcn_rcpf(1.f + __builtin_amdgcn_exp2f(-1.44269504f * prez));
      const float pren = __half2float(cxn0) + bXn + r * (an0 + bHn);
      const float e2 = __builtin_amdgcn_exp2f(2.88539008f * pren);
      const float n = 1.f - 2.f * __builtin_amdgcn_rcpf(e2 + 1.f);
      hr0 = n + z * (hr0 - n);
    }
    // gate math, batch 1
    {
      const float prer = ar1 + __half2float(cxr1) + bR;
      const float prez = az1 + __half2float(cxz1) + bZ;
      const float r = __builtin_amdgcn_rcpf(1.f + __builtin_amdgcn_exp2f(-1.44269504f * prer));
      const float z = __builtin_amdgcn_rcpf(1.f + __builtin_amdgcn_exp2f(-1.44269504f * prez));
      const float pren = __half2float(cxn1) + bXn + r * (an1 + bHn);
      const float e2 = __builtin_amdgcn_exp2f(2.88539008f * pren);
      const float n = 1.f - 2.f * __builtin_amdgcn_rcpf(e2 + 1.f);
      hr1 = n + z * (hr1 - n);
    }

    if (half == 0) {
      char* wb = &hbc[cur ^ 1][0][0];
      *(unsigned short*)(wb + wboff) = f16bits(hr0);
      *(unsigned short*)(wb + 512 + wboff) = f16bits(hr1);
      const int t = d ? 511 - s : s;
      const size_t orow0 = (size_t)(t * 64 + b0) * 512 + (size_t)d * 256 + j;
      if (last) {
        dout[orow0] = hr0;
        dout[orow0 + 512] = hr1;
      } else {
        unsigned u0 = __builtin_bit_cast(unsigned, hr0);
        u0 += 0x7fffu + ((u0 >> 16) & 1u);
        yout[orow0] = (unsigned short)(u0 >> 16);
        unsigned u1 = __builtin_bit_cast(unsigned, hr1);
        u1 += 0x7fffu + ((u1 >> 16) & 1u);
        yout[orow0 + 512] = (unsigned short)(u1 >> 16);
      }
    }
    cxr0 = nxr0; cxz0 = nxz0; cxn0 = nxn0;
    cxr1 = nxr1; cxz1 = nxz1; cxn1 = nxn1;
    __syncthreads();
  }

  // final hidden state -> h_n region
  if (half == 0) {
    dout[16777216 + (size_t)ld * 16384 + b0 * 256 + j] = hr0;
    dout[16777216 + (size_t)ld * 16384 + b1 * 256 + j] = hr1;
  }
}

// ---------------- launcher ----------------
extern "C" void kernel_launch(void* const* d_in, const int* in_sizes, int n_in,
                              void* d_out, int out_size, void* d_ws, size_t ws_size,
                              hipStream_t stream) {
  const float* x    = (const float*)d_in[0];
  const float* h0   = (const float*)d_in[1];
  const float* wih0 = (const float*)d_in[2];
  const float* whh0 = (const float*)d_in[3];
  const float* bih0 = (const float*)d_in[4];
  const float* bhh0 = (const float*)d_in[5];
  const float* wihr = (const float*)d_in[6];
  const float* whhr = (const float*)d_in[7];
  const float* bihr = (const float*)d_in[8];
  const float* bhhr = (const float*)d_in[9];

  char* ws = (char*)d_ws;
  __half*        xg    = (__half*)(ws + XG_OFF);
  unsigned short* x0   = (unsigned short*)(ws + X0_OFF);
  unsigned short* yA   = (unsigned short*)(ws + YA_OFF);
  unsigned short* yB   = (unsigned short*)(ws + YB_OFF);
  unsigned short* wih0b= (unsigned short*)(ws + WIH0_OFF);
  unsigned short* wihrb= (unsigned short*)(ws + WIHR_OFF);
  unsigned int*  wscan = (unsigned int*)(ws + WSCAN_OFF);
  float*         bias4 = (float*)(ws + BIAS_OFF);
  float*         dout  = (float*)d_out;

  cvt_bf16<<<4096, 256, 0, stream>>>(x, x0, M_ * I_);
  cvt_bf16<<<768, 256, 0, stream>>>(wih0, wih0b, 2 * 768 * 128);
  cvt_bf16<<<4096, 256, 0, stream>>>(wihr, wihrb, 5 * 2 * 768 * 512);
  prep_wscan<<<4608, 256, 0, stream>>>(whh0, whhr, wscan);
  prep_bias<<<48, 256, 0, stream>>>(bih0, bhh0, bihr, bhhr, bias4);

  for (int l = 0; l < L_; l++) {
    unsigned short* yw = (l & 1) ? yB : yA;                        // scan l writes
    const unsigned short* A = (l == 0) ? x0 : ((l & 1) ? yA : yB); // gemm l reads scan l-1's out
    const int K = (l == 0) ? 128 : 512;
    const unsigned short* W = (l == 0) ? wih0b : wihrb + (size_t)(l - 1) * 2 * 768 * 512;

    gemm_bt<<<dim3(256, 6, 2), 256, 0, stream>>>(A, W, xg, K);
    gru_scan3<<<dim3(32, 2), 512, 0, stream>>>(wscan, bias4, xg, h0, yw, dout, l, l == L_ - 1);
  }
}

// Round 11
// 6649.010 us; speedup vs baseline: 5.3792x; 5.3792x over previous
//
#include <hip/hip_runtime.h>
#include <hip/hip_fp16.h>

// ---------------- types ----------------
typedef short bf16x8 __attribute__((ext_vector_type(8)));
typedef float f32x4  __attribute__((ext_vector_type(4)));
typedef _Float16 h2_t __attribute__((ext_vector_type(2)));

#define T_ 512
#define B_ 64
#define I_ 128
#define H_ 256
#define L_ 6
#define M_ 32768  // T*B

// ---- workspace offsets (bytes), all 256-aligned ----
static constexpr size_t XG_OFF    = 0;
static constexpr size_t X0_OFF    = 100663296;
static constexpr size_t YA_OFF    = 109051904;
static constexpr size_t YB_OFF    = 142606336;
static constexpr size_t WIH0_OFF  = 176160768;
static constexpr size_t WIHR_OFF  = 176553984;
static constexpr size_t WSCAN_OFF = 184418304;
static constexpr size_t BIAS_OFF  = 189136896;

// ---------------- prep kernels ----------------
__global__ void cvt_bf16(const float* __restrict__ s, unsigned short* __restrict__ d, int n) {
  for (int i = blockIdx.x * blockDim.x + threadIdx.x; i < n; i += gridDim.x * blockDim.x) {
    unsigned u = __builtin_bit_cast(unsigned, s[i]);
    u += 0x7fffu + ((u >> 16) & 1u);
    d[i] = (unsigned short)(u >> 16);
  }
}

// r8-PROVEN layout (j is the lane-fast axis -> coalesced 256B/instr):
// wscan[ld][gate][r][j] = (f16(w_hh[gate*256+j][2r]), f16(w_hh[gate*256+j][2r+1]))
__global__ void prep_wscan(const float* __restrict__ whh0, const float* __restrict__ whhr,
                           unsigned int* __restrict__ out) {
  int idx = blockIdx.x * 256 + threadIdx.x;            // 12*3*128*256 = 1179648 exact
  int ld  = idx / 98304;
  int rem = idx - ld * 98304;
  int tg  = rem >> 15;
  int r   = (rem >> 8) & 127;
  int j   = rem & 255;
  const float* src = (ld < 2) ? (whh0 + (size_t)ld * 196608) : (whhr + (size_t)(ld - 2) * 196608);
  const float* row = src + (size_t)(tg * 256 + j) * 256;
  h2_t p; p[0] = (_Float16)row[2 * r]; p[1] = (_Float16)row[2 * r + 1];
  out[idx] = __builtin_bit_cast(unsigned int, p);
}

// bias4[ld][c][j]: c0 = bih_r+bhh_r, c1 = bih_z+bhh_z, c2 = bih_n, c3 = bhh_n
__global__ void prep_bias(const float* __restrict__ bih0, const float* __restrict__ bhh0,
                          const float* __restrict__ bihr, const float* __restrict__ bhhr,
                          float* __restrict__ out) {
  int idx = blockIdx.x * 256 + threadIdx.x;            // 12*4*256 = 12288 exact
  int ld = idx >> 10;
  int c  = (idx >> 8) & 3;
  int j  = idx & 255;
  const float* bi = (ld < 2) ? bih0 + ld * 768 : bihr + (ld - 2) * 768;
  const float* bh = (ld < 2) ? bhh0 + ld * 768 : bhhr + (ld - 2) * 768;
  float v;
  if (c == 0)      v = bi[j] + bh[j];
  else if (c == 1) v = bi[256 + j] + bh[256 + j];
  else if (c == 2) v = bi[512 + j];
  else             v = bh[512 + j];
  out[idx] = v;
}

// ---------------- GEMM: C[m,g] = sum_k A[m,k]*W[g,k], bf16 in, f16 out ----------------
__device__ __forceinline__ void llds16(const void* g, void* l) {
  __builtin_amdgcn_global_load_lds((const __attribute__((address_space(1))) void*)g,
                                   (__attribute__((address_space(3))) void*)l, 16, 0, 0);
}

__global__ __launch_bounds__(256)
void gemm_bt(const unsigned short* __restrict__ A,    // [M][K] bf16
             const unsigned short* __restrict__ Wl,   // [2][768][K] bf16
             __half* __restrict__ xg,                 // [2][M][768] f16
             int K) {
  const int m0 = blockIdx.x * 128;
  const int n0 = blockIdx.y * 128;
  const int d  = blockIdx.z;
  const unsigned short* W = Wl + (size_t)d * 768 * K;
  __half* C = xg + (size_t)d * M_ * 768;

  __shared__ short As[128 * 64];
  __shared__ short Bs[128 * 64];

  const int tid  = threadIdx.x;
  const int lane = tid & 63;

  const int wv = tid >> 6;
  const int wm = wv >> 1, wn = wv & 1;   // 2x2 wave grid, 64x64 per wave

  f32x4 acc[4][4] = {};

  for (int kt = 0; kt < K; kt += 64) {
#pragma unroll
    for (int i = 0; i < 4; i++) {        // stage A tile (128x64)
      int e = i * 256 + tid;
      int r = e >> 3, c = (e & 7) << 3;
      llds16(A + (size_t)(m0 + r) * K + kt + c, &As[e * 8]);
    }
#pragma unroll
    for (int i = 0; i < 4; i++) {        // stage W tile (128x64)
      int e = i * 256 + tid;
      int r = e >> 3, c = (e & 7) << 3;
      llds16(W + (size_t)(n0 + r) * K + kt + c, &Bs[e * 8]);
    }
    __syncthreads();
#pragma unroll
    for (int kf = 0; kf < 2; ++kf) {
      bf16x8 a[4], b[4];
      const int krow = kf * 32 + ((lane >> 4) << 3);
#pragma unroll
      for (int f = 0; f < 4; ++f)
        a[f] = *(const bf16x8*)&As[(wm * 64 + f * 16 + (lane & 15)) * 64 + krow];
#pragma unroll
      for (int f = 0; f < 4; ++f)
        b[f] = *(const bf16x8*)&Bs[(wn * 64 + f * 16 + (lane & 15)) * 64 + krow];
#pragma unroll
      for (int i = 0; i < 4; i++)
#pragma unroll
        for (int jn = 0; jn < 4; jn++)
          acc[i][jn] = __builtin_amdgcn_mfma_f32_16x16x32_bf16(a[i], b[jn], acc[i][jn], 0, 0, 0);
    }
    __syncthreads();
  }
  // epilogue: D col = lane&15, row = (lane>>4)*4 + v
#pragma unroll
  for (int i = 0; i < 4; i++) {
    const int row_b = m0 + wm * 64 + i * 16 + ((lane >> 4) << 2);
#pragma unroll
    for (int jn = 0; jn < 4; jn++) {
      const int col = n0 + wn * 64 + jn * 16 + (lane & 15);
#pragma unroll
      for (int v = 0; v < 4; ++v)
        C[(size_t)(row_b + v) * 768 + col] = __float2half(acc[i][jn][v]);
    }
  }
}

// ---------------- recurrent scan: one WG per (batch-PAIR, dir) ----------------
// NB=2 amortization ON THE r8 STRUCTURE (r10's relayout broke coalescing; this
// keeps r8's j-fast weight layout and swizzled h-LDS verbatim). r8 was chip-L2
// bound: 128 WGs x 393KB/step / 2690cy = 45 TB/s aggregate (>= L2 ceiling).
// 2 chains/WG -> 64 WGs: chip demand halves; per-XCD rate stays at the PROVEN
// 2.34 KB/cy -> step ~1345cy from L2 side; VALU doubles to ~1960cy (new floor).
#define FDOT2(a, b, c) __builtin_amdgcn_fdot2((a), (b), (c), false)
#define BC2(u) __builtin_bit_cast(h2_t, (u))

__device__ __forceinline__ float dpp_xor1(float x) {
  // quad_perm [1,0,3,2] = 0xB1 : swap adjacent lanes (VALU pipe, not LDS)
  int r = __builtin_amdgcn_update_dpp(0, __builtin_bit_cast(int, x), 0xB1, 0xF, 0xF, true);
  return __builtin_bit_cast(float, r);
}

__device__ __forceinline__ unsigned short f16bits(float f) {
  return __half_as_ushort(__float2half(f));
}

__global__
__attribute__((amdgpu_flat_work_group_size(512, 512)))
__attribute__((amdgpu_waves_per_eu(2, 2)))   // forces 1 WG/CU -> spread across 64 CUs
void gru_scan4(const unsigned int* __restrict__ wscan,  // [12][3][128][256]
               const float* __restrict__ bias4,         // [12][4][256]
               const __half* __restrict__ xg,           // [2][M][768]
               const float* __restrict__ h0,            // [12][64][256]
               unsigned short* __restrict__ yout,       // [M][512] bf16 (next-layer input)
               float* __restrict__ dout,                // d_out base (f32)
               int layer, int last) {
  const int tid  = threadIdx.x;
  const int j    = tid >> 1;    // h column / gate triple owner
  const int half = tid & 1;     // K-half
  const int bg   = blockIdx.x;  // batch pair
  const int b0   = bg * 2, b1 = b0 + 1;
  const int d    = blockIdx.y;  // direction
  const int ld   = layer * 2 + d;

  // w_hh rows (r,z,n for column j, k-half) -> 192 u32 (streamed; each value
  // feeds BOTH batches' fdot2 -> 2x MACs per byte vs r8)
  unsigned int wr[64], wz[64], wn_[64];
  {
    const unsigned int* wb = wscan + (size_t)ld * 98304 + (size_t)half * 64 * 256 + j;
#pragma unroll
    for (int r = 0; r < 64; r++) wr[r]  = wb[r * 256];
#pragma unroll
    for (int r = 0; r < 64; r++) wz[r]  = wb[32768 + r * 256];
#pragma unroll
    for (int r = 0; r < 64; r++) wn_[r] = wb[65536 + r * 256];
  }
#pragma unroll
  for (int r = 0; r < 64; r++) {
    asm volatile("" : "+v"(wr[r]));   // r8-proven: becomes an in-loop coalesced stream
    asm volatile("" : "+v"(wz[r]));
    asm volatile("" : "+v"(wn_[r]));
  }

  const float* bb = bias4 + ld * 1024;
  const float bR = bb[j], bZ = bb[256 + j], bXn = bb[512 + j], bHn = bb[768 + j];

  __shared__ __attribute__((aligned(16))) char hbc[2][2][512];  // [buf][m][swizzled 256 f16]

  // swizzled byte offset for h[j] (upper 256B block gets bit4 flipped) — r8-proven
  const int wboff   = (j * 2) ^ ((j & 128) >> 3);
  const int halfoff = half << 8;

  float hr0 = h0[(size_t)ld * 16384 + b0 * 256 + j];
  float hr1 = h0[(size_t)ld * 16384 + b1 * 256 + j];
  if (half == 0) {
    *(unsigned short*)(&hbc[0][0][0] + wboff) = f16bits(hr0);
    *(unsigned short*)(&hbc[0][1][0] + wboff) = f16bits(hr1);
  }

  const __half* xth = xg + (size_t)d * M_ * 768 + (size_t)b0 * 768 + j;
  const int t0 = d ? 511 : 0;
  size_t xo = (size_t)t0 * 49152;
  __half cxr0 = xth[xo], cxz0 = xth[xo + 256], cxn0 = xth[xo + 512];
  __half cxr1 = xth[xo + 768], cxz1 = xth[xo + 1024], cxn1 = xth[xo + 1280];

  __syncthreads();

#define DOT2(q)                                                                   \
  {                                                                               \
    const uint4 h0v = *(const uint4*)(rb + halfoff + ((((q) ^ half)) << 4));      \
    const uint4 h1v = *(const uint4*)(rb + 512 + halfoff + ((((q) ^ half)) << 4));\
    _Pragma("unroll")                                                             \
    for (int e = 0; e < 4; e++) {                                                 \
      const unsigned he0 = (&h0v.x)[e], he1 = (&h1v.x)[e];                        \
      ar0 = FDOT2(BC2(he0), BC2(wr[4 * (q) + e]), ar0);                           \
      az0 = FDOT2(BC2(he0), BC2(wz[4 * (q) + e]), az0);                           \
      an0 = FDOT2(BC2(he0), BC2(wn_[4 * (q) + e]), an0);                          \
      ar1 = FDOT2(BC2(he1), BC2(wr[4 * (q) + e]), ar1);                           \
      az1 = FDOT2(BC2(he1), BC2(wz[4 * (q) + e]), az1);                           \
      an1 = FDOT2(BC2(he1), BC2(wn_[4 * (q) + e]), an1);                          \
    }                                                                             \
  }
#define AFENCE asm volatile("" : "+v"(ar0), "+v"(az0), "+v"(an0),                 \
                                 "+v"(ar1), "+v"(az1), "+v"(an1) :: "memory")

  for (int s = 0; s < 512; s++) {
    const int cur = s & 1;
    // prefetch next step's xg (both batches)
    const int sn = (s + 1) & 511;
    const int t1 = d ? 511 - sn : sn;
    const size_t xo1 = (size_t)t1 * 49152;
    const __half nxr0 = xth[xo1], nxz0 = xth[xo1 + 256], nxn0 = xth[xo1 + 512];
    const __half nxr1 = xth[xo1 + 768], nxz1 = xth[xo1 + 1024], nxn1 = xth[xo1 + 1280];

    float ar0 = 0.f, az0 = 0.f, an0 = 0.f;
    float ar1 = 0.f, az1 = 0.f, an1 = 0.f;
    const char* rb = (const char*)&hbc[cur][0][0];

    DOT2(0);  DOT2(1);  DOT2(2);  DOT2(3);  AFENCE;
    DOT2(4);  DOT2(5);  DOT2(6);  DOT2(7);  AFENCE;
    DOT2(8);  DOT2(9);  DOT2(10); DOT2(11); AFENCE;
    DOT2(12); DOT2(13); DOT2(14); DOT2(15);

    // combine K-halves: partner is the adjacent lane
    ar0 += dpp_xor1(ar0); az0 += dpp_xor1(az0); an0 += dpp_xor1(an0);
    ar1 += dpp_xor1(ar1); az1 += dpp_xor1(az1); an1 += dpp_xor1(an1);

    // gate math, batch 0
    {
      const float prer = ar0 + __half2float(cxr0) + bR;
      const float prez = az0 + __half2float(cxz0) + bZ;
      const float r = __builtin_amdgcn_rcpf(1.f + __builtin_amdgcn_exp2f(-1.44269504f * prer));
      const float z = __builtin_amdgcn_rcpf(1.f + __builtin_amdgcn_exp2f(-1.44269504f * prez));
      const float pren = __half2float(cxn0) + bXn + r * (an0 + bHn);
      const float e2 = __builtin_amdgcn_exp2f(2.88539008f * pren);
      const float n = 1.f - 2.f * __builtin_amdgcn_rcpf(e2 + 1.f);
      hr0 = n + z * (hr0 - n);
    }
    // gate math, batch 1
    {
      const float prer = ar1 + __half2float(cxr1) + bR;
      const float prez = az1 + __half2float(cxz1) + bZ;
      const float r = __builtin_amdgcn_rcpf(1.f + __builtin_amdgcn_exp2f(-1.44269504f * prer));
      const float z = __builtin_amdgcn_rcpf(1.f + __builtin_amdgcn_exp2f(-1.44269504f * prez));
      const float pren = __half2float(cxn1) + bXn + r * (an1 + bHn);
      const float e2 = __builtin_amdgcn_exp2f(2.88539008f * pren);
      const float n = 1.f - 2.f * __builtin_amdgcn_rcpf(e2 + 1.f);
      hr1 = n + z * (hr1 - n);
    }

    if (half == 0) {
      char* wb = &hbc[cur ^ 1][0][0];
      *(unsigned short*)(wb + wboff) = f16bits(hr0);
      *(unsigned short*)(wb + 512 + wboff) = f16bits(hr1);
      const int t = d ? 511 - s : s;
      const size_t orow0 = (size_t)(t * 64 + b0) * 512 + (size_t)d * 256 + j;
      if (last) {
        dout[orow0] = hr0;
        dout[orow0 + 512] = hr1;
      } else {
        unsigned u0 = __builtin_bit_cast(unsigned, hr0);
        u0 += 0x7fffu + ((u0 >> 16) & 1u);
        yout[orow0] = (unsigned short)(u0 >> 16);
        unsigned u1 = __builtin_bit_cast(unsigned, hr1);
        u1 += 0x7fffu + ((u1 >> 16) & 1u);
        yout[orow0 + 512] = (unsigned short)(u1 >> 16);
      }
    }
    cxr0 = nxr0; cxz0 = nxz0; cxn0 = nxn0;
    cxr1 = nxr1; cxz1 = nxz1; cxn1 = nxn1;
    __syncthreads();
  }
#undef DOT2
#undef AFENCE

  // final hidden state -> h_n region
  if (half == 0) {
    dout[16777216 + (size_t)ld * 16384 + b0 * 256 + j] = hr0;
    dout[16777216 + (size_t)ld * 16384 + b1 * 256 + j] = hr1;
  }
}

// ---------------- launcher ----------------
extern "C" void kernel_launch(void* const* d_in, const int* in_sizes, int n_in,
                              void* d_out, int out_size, void* d_ws, size_t ws_size,
                              hipStream_t stream) {
  const float* x    = (const float*)d_in[0];
  const float* h0   = (const float*)d_in[1];
  const float* wih0 = (const float*)d_in[2];
  const float* whh0 = (const float*)d_in[3];
  const float* bih0 = (const float*)d_in[4];
  const float* bhh0 = (const float*)d_in[5];
  const float* wihr = (const float*)d_in[6];
  const float* whhr = (const float*)d_in[7];
  const float* bihr = (const float*)d_in[8];
  const float* bhhr = (const float*)d_in[9];

  char* ws = (char*)d_ws;
  __half*        xg    = (__half*)(ws + XG_OFF);
  unsigned short* x0   = (unsigned short*)(ws + X0_OFF);
  unsigned short* yA   = (unsigned short*)(ws + YA_OFF);
  unsigned short* yB   = (unsigned short*)(ws + YB_OFF);
  unsigned short* wih0b= (unsigned short*)(ws + WIH0_OFF);
  unsigned short* wihrb= (unsigned short*)(ws + WIHR_OFF);
  unsigned int*  wscan = (unsigned int*)(ws + WSCAN_OFF);
  float*         bias4 = (float*)(ws + BIAS_OFF);
  float*         dout  = (float*)d_out;

  cvt_bf16<<<4096, 256, 0, stream>>>(x, x0, M_ * I_);
  cvt_bf16<<<768, 256, 0, stream>>>(wih0, wih0b, 2 * 768 * 128);
  cvt_bf16<<<4096, 256, 0, stream>>>(wihr, wihrb, 5 * 2 * 768 * 512);
  prep_wscan<<<4608, 256, 0, stream>>>(whh0, whhr, wscan);
  prep_bias<<<48, 256, 0, stream>>>(bih0, bhh0, bihr, bhhr, bias4);

  for (int l = 0; l < L_; l++) {
    unsigned short* yw = (l & 1) ? yB : yA;                        // scan l writes
    const unsigned short* A = (l == 0) ? x0 : ((l & 1) ? yA : yB); // gemm l reads scan l-1's out
    const int K = (l == 0) ? 128 : 512;
    const unsigned short* W = (l == 0) ? wih0b : wihrb + (size_t)(l - 1) * 2 * 768 * 512;

    gemm_bt<<<dim3(256, 6, 2), 256, 0, stream>>>(A, W, xg, K);
    gru_scan4<<<dim3(32, 2), 512, 0, stream>>>(wscan, bias4, xg, h0, yw, dout, l, l == L_ - 1);
  }
}

// Round 12
// 3735.818 us; speedup vs baseline: 9.5739x; 1.7798x over previous
//
#include <hip/hip_runtime.h>
#include <hip/hip_fp16.h>

// ---------------- types ----------------
typedef short bf16x8 __attribute__((ext_vector_type(8)));
typedef float f32x4  __attribute__((ext_vector_type(4)));
typedef _Float16 h2_t __attribute__((ext_vector_type(2)));

#define T_ 512
#define B_ 64
#define I_ 128
#define H_ 256
#define L_ 6
#define M_ 32768  // T*B

// ---- workspace offsets (bytes), all 256-aligned ----
static constexpr size_t XG_OFF    = 0;
static constexpr size_t X0_OFF    = 100663296;
static constexpr size_t YA_OFF    = 109051904;
static constexpr size_t YB_OFF    = 142606336;
static constexpr size_t WIH0_OFF  = 176160768;
static constexpr size_t WIHR_OFF  = 176553984;
static constexpr size_t WSCAN_OFF = 184418304;
static constexpr size_t BIAS_OFF  = 189136896;

// ---------------- prep kernels ----------------
__global__ void cvt_bf16(const float* __restrict__ s, unsigned short* __restrict__ d, int n) {
  for (int i = blockIdx.x * blockDim.x + threadIdx.x; i < n; i += gridDim.x * blockDim.x) {
    unsigned u = __builtin_bit_cast(unsigned, s[i]);
    u += 0x7fffu + ((u >> 16) & 1u);
    d[i] = (unsigned short)(u >> 16);
  }
}

// wscan[ld][gate][r][j] = (f16(w_hh[gate*256+j][2r]), f16(w_hh[gate*256+j][2r+1]))
__global__ void prep_wscan(const float* __restrict__ whh0, const float* __restrict__ whhr,
                           unsigned int* __restrict__ out) {
  int idx = blockIdx.x * 256 + threadIdx.x;            // 12*3*128*256 = 1179648 exact
  int ld  = idx / 98304;
  int rem = idx - ld * 98304;
  int tg  = rem >> 15;
  int r   = (rem >> 8) & 127;
  int j   = rem & 255;
  const float* src = (ld < 2) ? (whh0 + (size_t)ld * 196608) : (whhr + (size_t)(ld - 2) * 196608);
  const float* row = src + (size_t)(tg * 256 + j) * 256;
  h2_t p; p[0] = (_Float16)row[2 * r]; p[1] = (_Float16)row[2 * r + 1];
  out[idx] = __builtin_bit_cast(unsigned int, p);
}

// bias4[ld][c][j]: c0 = bih_r+bhh_r, c1 = bih_z+bhh_z, c2 = bih_n, c3 = bhh_n
__global__ void prep_bias(const float* __restrict__ bih0, const float* __restrict__ bhh0,
                          const float* __restrict__ bihr, const float* __restrict__ bhhr,
                          float* __restrict__ out) {
  int idx = blockIdx.x * 256 + threadIdx.x;            // 12*4*256 = 12288 exact
  int ld = idx >> 10;
  int c  = (idx >> 8) & 3;
  int j  = idx & 255;
  const float* bi = (ld < 2) ? bih0 + ld * 768 : bihr + (ld - 2) * 768;
  const float* bh = (ld < 2) ? bhh0 + ld * 768 : bhhr + (ld - 2) * 768;
  float v;
  if (c == 0)      v = bi[j] + bh[j];
  else if (c == 1) v = bi[256 + j] + bh[256 + j];
  else if (c == 2) v = bi[512 + j];
  else             v = bh[512 + j];
  out[idx] = v;
}

// ---------------- GEMM: C[m,g] = sum_k A[m,k]*W[g,k], bf16 in, f16 out ----------------
__device__ __forceinline__ void llds16(const void* g, void* l) {
  __builtin_amdgcn_global_load_lds((const __attribute__((address_space(1))) void*)g,
                                   (__attribute__((address_space(3))) void*)l, 16, 0, 0);
}

__global__ __launch_bounds__(256)
void gemm_bt(const unsigned short* __restrict__ A,    // [M][K] bf16
             const unsigned short* __restrict__ Wl,   // [2][768][K] bf16
             __half* __restrict__ xg,                 // [2][M][768] f16
             int K) {
  const int m0 = blockIdx.x * 128;
  const int n0 = blockIdx.y * 128;
  const int d  = blockIdx.z;
  const unsigned short* W = Wl + (size_t)d * 768 * K;
  __half* C = xg + (size_t)d * M_ * 768;

  __shared__ short As[128 * 64];
  __shared__ short Bs[128 * 64];

  const int tid  = threadIdx.x;
  const int lane = tid & 63;

  const int wv = tid >> 6;
  const int wm = wv >> 1, wn = wv & 1;   // 2x2 wave grid, 64x64 per wave

  f32x4 acc[4][4] = {};

  for (int kt = 0; kt < K; kt += 64) {
#pragma unroll
    for (int i = 0; i < 4; i++) {        // stage A tile (128x64)
      int e = i * 256 + tid;
      int r = e >> 3, c = (e & 7) << 3;
      llds16(A + (size_t)(m0 + r) * K + kt + c, &As[e * 8]);
    }
#pragma unroll
    for (int i = 0; i < 4; i++) {        // stage W tile (128x64)
      int e = i * 256 + tid;
      int r = e >> 3, c = (e & 7) << 3;
      llds16(W + (size_t)(n0 + r) * K + kt + c, &Bs[e * 8]);
    }
    __syncthreads();
#pragma unroll
    for (int kf = 0; kf < 2; ++kf) {
      bf16x8 a[4], b[4];
      const int krow = kf * 32 + ((lane >> 4) << 3);
#pragma unroll
      for (int f = 0; f < 4; ++f)
        a[f] = *(const bf16x8*)&As[(wm * 64 + f * 16 + (lane & 15)) * 64 + krow];
#pragma unroll
      for (int f = 0; f < 4; ++f)
        b[f] = *(const bf16x8*)&Bs[(wn * 64 + f * 16 + (lane & 15)) * 64 + krow];
#pragma unroll
      for (int i = 0; i < 4; i++)
#pragma unroll
        for (int jn = 0; jn < 4; jn++)
          acc[i][jn] = __builtin_amdgcn_mfma_f32_16x16x32_bf16(a[i], b[jn], acc[i][jn], 0, 0, 0);
    }
    __syncthreads();
  }
  // epilogue: D col = lane&15, row = (lane>>4)*4 + v
#pragma unroll
  for (int i = 0; i < 4; i++) {
    const int row_b = m0 + wm * 64 + i * 16 + ((lane >> 4) << 2);
#pragma unroll
    for (int jn = 0; jn < 4; jn++) {
      const int col = n0 + wn * 64 + jn * 16 + (lane & 15);
#pragma unroll
      for (int v = 0; v < 4; ++v)
        C[(size_t)(row_b + v) * 768 + col] = __float2half(acc[i][jn][v]);
    }
  }
}

// ---------------- recurrent scan: one WG per (b, dir) chain ----------------
// FINAL (r7 configuration — measured best, 573us/dispatch):
// 512 threads: thread (j, half) owns gates r/z/n for column j over k in
// [half*128, half*128+128). The 192 weight dwords/thread stream from L2 every
// step (residency is impossible: 393KB/chain > register-file share; proven by
// r2/r6/r7/r8/r9). Step time 2690cy == chip-L2 delivery roofline at 50MB/step
// (45 TB/s measured). NB>=2 batch-sharing loses on the issue pipe (r11);
// MFMA variants lose on matrix-pipe padding floor 1862cy/step (r3/r4/r5).
#define FDOT2(a, b, c) __builtin_amdgcn_fdot2((a), (b), (c), false)
#define BC2(u) __builtin_bit_cast(h2_t, (u))

__device__ __forceinline__ float dpp_xor1(float x) {
  // quad_perm [1,0,3,2] = 0xB1 : swap adjacent lanes (VALU pipe, not LDS)
  int r = __builtin_amdgcn_update_dpp(0, __builtin_bit_cast(int, x), 0xB1, 0xF, 0xF, true);
  return __builtin_bit_cast(float, r);
}

__global__ __launch_bounds__(512, 1)
void gru_scan2(const unsigned int* __restrict__ wscan,  // [12][3][128][256]
               const float* __restrict__ bias4,         // [12][4][256]
               const __half* __restrict__ xg,           // [2][M][768]
               const float* __restrict__ h0,            // [12][64][256]
               unsigned short* __restrict__ yout,       // [M][512] bf16 (next-layer input)
               float* __restrict__ dout,                // d_out base (f32)
               int layer, int last) {
  const int tid  = threadIdx.x;
  const int j    = tid >> 1;   // h column / gate triple owner
  const int half = tid & 1;    // K-half
  const int b    = blockIdx.x; // batch
  const int d    = blockIdx.y; // direction
  const int ld   = layer * 2 + d;

  // w_hh rows (r,z,n for column j, k-half) -> 192 u32 (stream; compiler stages
  // them via scratch-L2 with immediate-offset loads -- measured-equivalent to
  // direct L2 loads and saves per-load addressing)
  unsigned int wr[64], wz[64], wn_[64];
  {
    const unsigned int* wb = wscan + (size_t)ld * 98304 + (size_t)half * 64 * 256 + j;
#pragma unroll
    for (int r = 0; r < 64; r++) wr[r]  = wb[r * 256];
#pragma unroll
    for (int r = 0; r < 64; r++) wz[r]  = wb[32768 + r * 256];
#pragma unroll
    for (int r = 0; r < 64; r++) wn_[r] = wb[65536 + r * 256];
  }
  // Opaque redefinition: blocks load-rematerialization.
#pragma unroll
  for (int r = 0; r < 64; r++) {
    asm volatile("" : "+v"(wr[r]));
    asm volatile("" : "+v"(wz[r]));
    asm volatile("" : "+v"(wn_[r]));
  }

  const float* bb = bias4 + ld * 1024;
  const float bR = bb[j], bZ = bb[256 + j], bXn = bb[512 + j], bHn = bb[768 + j];

  __shared__ __attribute__((aligned(16))) char hbc[2][512];

  // swizzled byte offset for h[j] (upper 256B block gets bit4 flipped)
  const int wboff = (j * 2) ^ ((j & 128) >> 3);

  float h = h0[(size_t)ld * 16384 + b * 256 + j];
  if (half == 0) *(unsigned short*)(hbc[0] + wboff) = __half_as_ushort(__float2half(h));

  const __half* xgd = xg + (size_t)d * M_ * 768;
  const int t0 = d ? 511 : 0;
  size_t xb = (size_t)(t0 * 64 + b) * 768 + j;
  __half cxr = xgd[xb], cxz = xgd[xb + 256], cxn = xgd[xb + 512];

  const int halfoff = half << 8;

  __syncthreads();

#define RD(k) (*(const uint4*)(rb + halfoff + ((((k) ^ half)) << 4)))
#define DOT1(hv, q)                                          \
  {                                                          \
    ar = FDOT2(BC2((hv).x), BC2(wr[4*(q)+0]), ar);           \
    az = FDOT2(BC2((hv).x), BC2(wz[4*(q)+0]), az);           \
    an = FDOT2(BC2((hv).x), BC2(wn_[4*(q)+0]), an);          \
    ar = FDOT2(BC2((hv).y), BC2(wr[4*(q)+1]), ar);           \
    az = FDOT2(BC2((hv).y), BC2(wz[4*(q)+1]), az);           \
    an = FDOT2(BC2((hv).y), BC2(wn_[4*(q)+1]), an);          \
    ar = FDOT2(BC2((hv).z), BC2(wr[4*(q)+2]), ar);           \
    az = FDOT2(BC2((hv).z), BC2(wz[4*(q)+2]), az);           \
    an = FDOT2(BC2((hv).z), BC2(wn_[4*(q)+2]), an);          \
    ar = FDOT2(BC2((hv).w), BC2(wr[4*(q)+3]), ar);           \
    az = FDOT2(BC2((hv).w), BC2(wz[4*(q)+3]), az);           \
    an = FDOT2(BC2((hv).w), BC2(wn_[4*(q)+3]), an);          \
  }
// Fence tied to the accumulators: orders memory ops AND forces the preceding
// DOT block to retire first -> loads/DOTs interleave, in-flight lines <= ~5.
#define AFENCE asm volatile("" : "+v"(ar), "+v"(az), "+v"(an) :: "memory")

  for (int s = 0; s < 512; s++) {
    const int cur = s & 1;
    // prefetch next step's xg
    const int sn = (s + 1) & 511;
    const int t1 = d ? 511 - sn : sn;
    const size_t xb1 = (size_t)(t1 * 64 + b) * 768 + j;
    const __half nxr = xgd[xb1], nxz = xgd[xb1 + 256], nxn = xgd[xb1 + 512];

    float ar = 0.f, az = 0.f, an = 0.f;
    const char* rb = hbc[cur];

    uint4 lA = RD(0), lB = RD(1), lC = RD(2), lD = RD(3);
    AFENCE;
    DOT1(lA, 0);  AFENCE; lA = RD(4);
    DOT1(lB, 1);  AFENCE; lB = RD(5);
    DOT1(lC, 2);  AFENCE; lC = RD(6);
    DOT1(lD, 3);  AFENCE; lD = RD(7);
    DOT1(lA, 4);  AFENCE; lA = RD(8);
    DOT1(lB, 5);  AFENCE; lB = RD(9);
    DOT1(lC, 6);  AFENCE; lC = RD(10);
    DOT1(lD, 7);  AFENCE; lD = RD(11);
    DOT1(lA, 8);  AFENCE; lA = RD(12);
    DOT1(lB, 9);  AFENCE; lB = RD(13);
    DOT1(lC, 10); AFENCE; lC = RD(14);
    DOT1(lD, 11); AFENCE; lD = RD(15);
    DOT1(lA, 12); AFENCE;
    DOT1(lB, 13); AFENCE;
    DOT1(lC, 14); AFENCE;
    DOT1(lD, 15);

    // combine K-halves: partner is the adjacent lane
    ar += dpp_xor1(ar);
    az += dpp_xor1(az);
    an += dpp_xor1(an);

    const float prer = ar + __half2float(cxr) + bR;
    const float prez = az + __half2float(cxz) + bZ;
    const float r = __builtin_amdgcn_rcpf(1.f + __builtin_amdgcn_exp2f(-1.44269504f * prer));
    const float z = __builtin_amdgcn_rcpf(1.f + __builtin_amdgcn_exp2f(-1.44269504f * prez));
    const float pren = __half2float(cxn) + bXn + r * (an + bHn);
    const float e2 = __builtin_amdgcn_exp2f(2.88539008f * pren);
    const float n = 1.f - 2.f * __builtin_amdgcn_rcpf(e2 + 1.f);
    h = n + z * (h - n);

    if (half == 0) {
      *(unsigned short*)(hbc[cur ^ 1] + wboff) = __half_as_ushort(__float2half(h));
      const int t = d ? 511 - s : s;
      const size_t orow = (size_t)(t * 64 + b) * 512 + (size_t)d * 256 + j;
      if (last) {
        dout[orow] = h;
      } else {
        unsigned u = __builtin_bit_cast(unsigned, h);
        u += 0x7fffu + ((u >> 16) & 1u);
        yout[orow] = (unsigned short)(u >> 16);
      }
    }
    cxr = nxr; cxz = nxz; cxn = nxn;
    __syncthreads();
  }
#undef RD
#undef DOT1
#undef AFENCE
  // final hidden state -> h_n region
  if (half == 0) dout[16777216 + (size_t)ld * 16384 + b * 256 + j] = h;
}

// ---------------- launcher ----------------
extern "C" void kernel_launch(void* const* d_in, const int* in_sizes, int n_in,
                              void* d_out, int out_size, void* d_ws, size_t ws_size,
                              hipStream_t stream) {
  const float* x    = (const float*)d_in[0];
  const float* h0   = (const float*)d_in[1];
  const float* wih0 = (const float*)d_in[2];
  const float* whh0 = (const float*)d_in[3];
  const float* bih0 = (const float*)d_in[4];
  const float* bhh0 = (const float*)d_in[5];
  const float* wihr = (const float*)d_in[6];
  const float* whhr = (const float*)d_in[7];
  const float* bihr = (const float*)d_in[8];
  const float* bhhr = (const float*)d_in[9];

  char* ws = (char*)d_ws;
  __half*        xg    = (__half*)(ws + XG_OFF);
  unsigned short* x0   = (unsigned short*)(ws + X0_OFF);
  unsigned short* yA   = (unsigned short*)(ws + YA_OFF);
  unsigned short* yB   = (unsigned short*)(ws + YB_OFF);
  unsigned short* wih0b= (unsigned short*)(ws + WIH0_OFF);
  unsigned short* wihrb= (unsigned short*)(ws + WIHR_OFF);
  unsigned int*  wscan = (unsigned int*)(ws + WSCAN_OFF);
  float*         bias4 = (float*)(ws + BIAS_OFF);
  float*         dout  = (float*)d_out;

  cvt_bf16<<<4096, 256, 0, stream>>>(x, x0, M_ * I_);
  cvt_bf16<<<768, 256, 0, stream>>>(wih0, wih0b, 2 * 768 * 128);
  cvt_bf16<<<4096, 256, 0, stream>>>(wihr, wihrb, 5 * 2 * 768 * 512);
  prep_wscan<<<4608, 256, 0, stream>>>(whh0, whhr, wscan);
  prep_bias<<<48, 256, 0, stream>>>(bih0, bhh0, bihr, bhhr, bias4);

  for (int l = 0; l < L_; l++) {
    unsigned short* yw = (l & 1) ? yB : yA;                        // scan l writes
    const unsigned short* A = (l == 0) ? x0 : ((l & 1) ? yA : yB); // gemm l reads scan l-1's out
    const int K = (l == 0) ? 128 : 512;
    const unsigned short* W = (l == 0) ? wih0b : wihrb + (size_t)(l - 1) * 2 * 768 * 512;

    gemm_bt<<<dim3(256, 6, 2), 256, 0, stream>>>(A, W, xg, K);
    gru_scan2<<<dim3(64, 2), 512, 0, stream>>>(wscan, bias4, xg, h0, yw, dout, l, l == L_ - 1);
  }
}